// Round 8
// baseline (183.213 us; speedup 1.0000x reference)
//
#include <hip/hip_runtime.h>
#include <hip/hip_bf16.h>

constexpr int Bt    = 131072;
constexpr int OBS   = 194;
constexpr int NT    = 512;   // 8 waves / block
constexpr int ITERS = 4;     // 8 waves * 16 rows * 4 = 512 rows per block
constexpr int RS    = 72;    // h row stride (shorts)
constexpr int LS    = 18;    // logit row stride (shorts)

// ---- d_ws: two role-contiguous fragment tables (shorts) ----
// role table: [L1 frags 14336][L2 frags 8192][head frags 1024] = 23552 shorts (47104 B)
// B-fragments for mfma_f32_16x16x32_bf16: frag (kb*4+nt)*64 + lane, 8 shorts each.
// L1: k<194 -> W[k][n]; k==194 -> bias[n] (A supplies 1.0); else 0.
// L2/head: k permuted by gamma(s) = (s&3)*16 + (s>>2) to match packed h layout.
// head frag cols 0-14 = Wh (col = e*5+a), col 15 = Wc3.
constexpr int ROLE_S = 23552;

// ---- LDS layout (bytes) ----
constexpr int L_W1f = 0;        // 28672
constexpr int L_W2f = 28672;    // 16384
constexpr int L_WHf = 45056;    //  2048
constexpr int L_H   = 47104;    // + w*2304  (8 waves -> 18432)
constexpr int L_AUX = 65536;    // + w*576   (actor: logits; critic: value buf)
constexpr int L_TOT = 70144;    // 2 blocks/CU -> 140288 <= 160 KiB

typedef short bf8   __attribute__((ext_vector_type(8)));
typedef float f32x4 __attribute__((ext_vector_type(4)));
typedef unsigned int u32;

__device__ __forceinline__ short f2bs(float f) {
    union { __hip_bfloat16 h; short s; } u;
    u.h = __float2bfloat16(f);
    return u.s;
}
__device__ __forceinline__ float bs2f(short s) {
    union { short s; __hip_bfloat16 h; } u;
    u.s = s;
    return __bfloat162float(u.h);
}
__device__ __forceinline__ u32 pk2(float a, float b) {
    union { __hip_bfloat162 h; u32 u; } r;
    r.h = __float22bfloat162_rn(float2{a, b});
    return r.u;
}
__device__ __forceinline__ float fast_tanh(float v) {
    v = fminf(fmaxf(v, -15.f), 15.f);
    float e = __expf(2.f * v);
    return (e - 1.f) * __builtin_amdgcn_rcpf(e + 1.f);
}
__device__ __forceinline__ void dma16(const void* g, void* s) {
    __builtin_amdgcn_global_load_lds(
        (const __attribute__((address_space(1))) u32*)g,
        (__attribute__((address_space(3))) u32*)s, 16, 0, 0);
}

// ---------------- prep: weights -> role-contiguous B-fragment tables ----------------
__global__ void __launch_bounds__(256) prep(
    const float* __restrict__ W1, const float* __restrict__ b1,
    const float* __restrict__ W2, const float* __restrict__ Wh,
    const float* __restrict__ Wc1, const float* __restrict__ bc1,
    const float* __restrict__ Wc2, const float* __restrict__ Wc3,
    short* __restrict__ ws)
{
    const int gid = blockIdx.x * 256 + threadIdx.x;
    const int gsz = gridDim.x * 256;

    for (int i = gid; i < 14336; i += gsz) {
        int j = i & 7, l = (i >> 3) & 63, nt = (i >> 9) & 3, kb = i >> 11;
        int k = kb * 32 + ((l >> 4) << 3) + j;
        int n = nt * 16 + (l & 15);
        short v1 = 0, v2 = 0;
        if (k < OBS) {
            v1 = f2bs(W1[k * 64 + n]);
            v2 = f2bs(Wc1[k * 64 + n]);
        } else if (k == OBS) {              // bias row (A supplies 1.0)
            v1 = f2bs(b1[n]);
            v2 = f2bs(bc1[n]);
        }
        ws[i]          = v1;
        ws[ROLE_S + i] = v2;
    }
    for (int i = gid; i < 8192; i += gsz) {
        int j = i & 7, l = (i >> 3) & 63, nt = (i >> 9) & 3, kb = i >> 11;
        int s = kb * 32 + ((l >> 4) << 3) + j;
        int kp = (s & 3) * 16 + (s >> 2);   // gamma(s)
        int n = nt * 16 + (l & 15);
        ws[14336 + i]          = f2bs(W2[kp * 64 + n]);
        ws[ROLE_S + 14336 + i] = f2bs(Wc2[kp * 64 + n]);
    }
    for (int i = gid; i < 1024; i += gsz) {
        int j = i & 7, l = (i >> 3) & 63, kb = i >> 9;
        int s = kb * 32 + ((l >> 4) << 3) + j;
        int kp = (s & 3) * 16 + (s >> 2);
        int cc = l & 15;
        float v;
        if (cc == 15) v = Wc3[kp];
        else { int e = cc / 5, a = cc - 5 * e; v = Wh[(e * 64 + kp) * 5 + a]; }
        short vs = f2bs(v);
        ws[22528 + i]          = vs;
        ws[ROLE_S + 22528 + i] = vs;
    }
}

// -------- main: role-specialized persistent blocks (2/CU), one barrier total --------
__global__ void __launch_bounds__(NT, 4) fused_ac(
    const float* __restrict__ x, const int* __restrict__ act_in,
    const float* __restrict__ b2, const float* __restrict__ bc2,
    const float* __restrict__ bh, const float* __restrict__ bc3,
    const short* __restrict__ ws,
    float* __restrict__ out)
{
    __shared__ __align__(16) char smem[L_TOT];

    const int t    = threadIdx.x;
    const int w    = t >> 6;
    const int l    = t & 63;
    const int q    = l >> 4;
    const int c    = l & 15;
    const int b    = blockIdx.x;
    // XCD pairing: actor b=g*16+sub, critic b=g*16+8+sub -> both on XCD (b%8)
    const int g    = b >> 4;
    const int role = (b >> 3) & 1;          // 0 = actor, 1 = critic
    const int sub  = b & 7;
    const int base = g * 4096 + sub * 512;

    // ---- single DMA of this role's 47104 B (2944 16-B chunks) ----
    {
        const char* gsrc = ((const char*)ws) + (size_t)role * 47104;
        #pragma unroll
        for (int i = 0; i < 6; ++i) {
            int idx = i * NT + t;
            if (idx < 2944)
                dma16(gsrc + idx * 16, smem + idx * 16);
        }
    }

    // ---- uniform prefetches (overlap DMA) ----
    const float* bL2 = role ? bc2 : b2;
    float b2v[4];
    #pragma unroll
    for (int nt = 0; nt < 4; ++nt) b2v[nt] = bL2[nt * 16 + c];
    float bhv = role ? bc3[0] : ((c < 15) ? bh[c] : 0.f);

    __syncthreads();                        // the only barrier: fragments resident

    const bf8* fL1 = reinterpret_cast<const bf8*>(smem + L_W1f);
    const bf8* fL2 = reinterpret_cast<const bf8*>(smem + L_W2f);
    const bf8* fWh = reinterpret_cast<const bf8*>(smem + L_WHf);
    short* hb = reinterpret_cast<short*>(smem + L_H + w * 2304);
    short* lw = reinterpret_cast<short*>(smem + L_AUX + w * 576);
    float* vb = reinterpret_cast<float*>(smem + L_AUX + w * 576);

    #pragma unroll 1
    for (int i = 0; i < ITERS; ++i) {
        const int gm = base + i * 128 + w * 16 + c;

        // ---- x row load (float2; rows are 8B-aligned) + act ----
        float2 raw[24]; float2 rt6 = float2{0.f, 0.f};
        {
            const float* xr = x + (size_t)gm * OBS;
            #pragma unroll
            for (int kb = 0; kb < 6; ++kb) {
                const float2* p = reinterpret_cast<const float2*>(xr + kb * 32 + q * 8);
                raw[kb * 4 + 0] = p[0]; raw[kb * 4 + 1] = p[1];
                raw[kb * 4 + 2] = p[2]; raw[kb * 4 + 3] = p[3];
            }
            if (q == 0) rt6 = *reinterpret_cast<const float2*>(xr + 192);
        }
        int act = 0;
        if (role == 0 && l < 16) act = act_in[gm];

        // ---- pack to A-fragments; argmax(x[0..2]) valid for q==0 lanes ----
        union AF { u32 u[4]; bf8 v; } af[7];
        #pragma unroll
        for (int kb = 0; kb < 6; ++kb) {
            af[kb].u[0] = pk2(raw[kb * 4 + 0].x, raw[kb * 4 + 0].y);
            af[kb].u[1] = pk2(raw[kb * 4 + 1].x, raw[kb * 4 + 1].y);
            af[kb].u[2] = pk2(raw[kb * 4 + 2].x, raw[kb * 4 + 2].y);
            af[kb].u[3] = pk2(raw[kb * 4 + 3].x, raw[kb * 4 + 3].y);
        }
        af[6].u[0] = 0; af[6].u[1] = 0; af[6].u[2] = 0; af[6].u[3] = 0;
        if (q == 0) {
            af[6].u[0] = pk2(rt6.x, rt6.y);
            af[6].u[1] = pk2(1.0f, 0.0f);   // k=194 -> 1.0 (bias row)
        }
        int ev = 0;
        {
            float bbest = raw[0].x;
            if (raw[0].y > bbest) { bbest = raw[0].y; ev = 1; }
            if (raw[1].x > bbest) { ev = 2; }
        }

        // ---- layer 1 (bias folded via k=194 row) ----
        f32x4 acc[4];
        #pragma unroll
        for (int nt = 0; nt < 4; ++nt) acc[nt] = f32x4{0.f, 0.f, 0.f, 0.f};
        #pragma unroll
        for (int kb = 0; kb < 7; ++kb) {
            bf8 a = af[kb].v;
            #pragma unroll
            for (int nt = 0; nt < 4; ++nt)
                acc[nt] = __builtin_amdgcn_mfma_f32_16x16x32_bf16(a, fL1[(kb * 4 + nt) * 64 + l], acc[nt], 0, 0, 0);
        }
        // tanh -> packed wave-local LDS (slot 4c+i = col i*16+c; gamma on B side)
        #pragma unroll
        for (int r = 0; r < 4; ++r) {
            uint2 pa;
            pa.x = pk2(fast_tanh(acc[0][r]), fast_tanh(acc[1][r]));
            pa.y = pk2(fast_tanh(acc[2][r]), fast_tanh(acc[3][r]));
            *reinterpret_cast<uint2*>(&hb[(q * 4 + r) * RS + 4 * c]) = pa;
        }

        // ---- layer 2 (bias via acc init) ----
        #pragma unroll
        for (int nt = 0; nt < 4; ++nt)
            acc[nt] = f32x4{b2v[nt], b2v[nt], b2v[nt], b2v[nt]};
        #pragma unroll
        for (int kb = 0; kb < 2; ++kb) {
            bf8 xa = *reinterpret_cast<const bf8*>(&hb[c * RS + kb * 32 + q * 8]);
            #pragma unroll
            for (int nt = 0; nt < 4; ++nt)
                acc[nt] = __builtin_amdgcn_mfma_f32_16x16x32_bf16(xa, fL2[(kb * 4 + nt) * 64 + l], acc[nt], 0, 0, 0);
        }
        #pragma unroll
        for (int r = 0; r < 4; ++r) {
            uint2 pa;
            pa.x = pk2(fast_tanh(acc[0][r]), fast_tanh(acc[1][r]));
            pa.y = pk2(fast_tanh(acc[2][r]), fast_tanh(acc[3][r]));
            *reinterpret_cast<uint2*>(&hb[(q * 4 + r) * RS + 4 * c]) = pa;
        }

        // ---- head: feat[16x64] @ [64x16] (cols 0-14 logits, col 15 value) ----
        {
            f32x4 hd = f32x4{bhv, bhv, bhv, bhv};
            #pragma unroll
            for (int kb = 0; kb < 2; ++kb) {
                bf8 bw = fWh[kb * 64 + l];
                bf8 fa = *reinterpret_cast<const bf8*>(&hb[c * RS + kb * 32 + q * 8]);
                hd = __builtin_amdgcn_mfma_f32_16x16x32_bf16(fa, bw, hd, 0, 0, 0);
            }
            if (role == 0) {
                #pragma unroll
                for (int r = 0; r < 4; ++r)
                    lw[(q * 4 + r) * LS + c] = f2bs(hd[r]);
            } else if (c == 15) {
                #pragma unroll
                for (int r = 0; r < 4; ++r)
                    vb[q * 4 + r] = hd[r];
            }
        }

        // ---- epilogue: lanes 0-15 (q==0 -> ev valid); wave-local LDS ----
        if (role == 0) {
            if (l < 16) {
                float lg[5];
                #pragma unroll
                for (int a = 0; a < 5; ++a)
                    lg[a] = bs2f(lw[c * LS + ev * 5 + a]);
                float mx = lg[0];
                #pragma unroll
                for (int a = 1; a < 5; ++a) mx = fmaxf(mx, lg[a]);
                float se = 0.f;
                #pragma unroll
                for (int a = 0; a < 5; ++a) se += __expf(lg[a] - mx);
                float lse = __logf(se) + mx;
                float lsel = lg[0];
                #pragma unroll
                for (int a = 1; a < 5; ++a) lsel = (act == a) ? lg[a] : lsel;
                float ent = 0.f;
                #pragma unroll
                for (int a = 0; a < 5; ++a) { float lp = lg[a] - lse; ent -= __expf(lp) * lp; }

                out[gm]          = (float)act;
                out[Bt + gm]     = lsel - lse;
                out[2 * Bt + gm] = ent;
            }
        } else {
            if (l < 16)
                out[3 * Bt + gm] = vb[c];
        }
    }
}

extern "C" void kernel_launch(void* const* d_in, const int* in_sizes, int n_in,
                              void* d_out, int out_size, void* d_ws, size_t ws_size,
                              hipStream_t stream) {
    const float* x   = (const float*)d_in[0];
    const int*   act = (const int*)  d_in[1];
    const float* W1  = (const float*)d_in[2];
    const float* b1  = (const float*)d_in[3];
    const float* W2  = (const float*)d_in[4];
    const float* b2  = (const float*)d_in[5];
    const float* Wh  = (const float*)d_in[6];
    const float* bh  = (const float*)d_in[7];
    const float* Wc1 = (const float*)d_in[8];
    const float* bc1 = (const float*)d_in[9];
    const float* Wc2 = (const float*)d_in[10];
    const float* bc2 = (const float*)d_in[11];
    const float* Wc3 = (const float*)d_in[12];
    const float* bc3 = (const float*)d_in[13];
    float* out = (float*)d_out;
    short* ws  = (short*)d_ws;

    hipLaunchKernelGGL(prep, dim3(32), dim3(256), 0, stream,
                       W1, b1, W2, Wh, Wc1, bc1, Wc2, Wc3, ws);
    hipLaunchKernelGGL(fused_ac, dim3(512), dim3(NT), 0, stream,
                       x, act, b2, bc2, bh, bc3, ws, out);
}